// Round 1
// baseline (31089.218 us; speedup 1.0000x reference)
//
#include <hip/hip_runtime.h>

typedef unsigned short ushort_t;

static constexpr int BATCH = 1024;
static constexpr int TT = 128;   // T
static constexpr int NN = 128;   // N
static constexpr int MM = 256;   // M == P

__device__ __forceinline__ float bf2f(ushort_t u) {
    union { unsigned int i; float f; } v;
    v.i = ((unsigned int)u) << 16;
    return v.f;
}
__device__ __forceinline__ ushort_t f2bf(float f) {
    union { unsigned int i; float f; } v;
    v.f = f;
    unsigned int i = v.i;
    return (ushort_t)((i + 0x7FFFu + ((i >> 16) & 1u)) >> 16);
}
__device__ __forceinline__ float tanh_fast(float x) {
    x = fminf(9.0f, fmaxf(-9.0f, x));
    float e = __expf(2.0f * x);
    return 1.0f - __fdividef(2.0f, e + 1.0f);
}
__device__ __forceinline__ float sig_fast(float x) {
    x = fminf(30.0f, fmaxf(-30.0f, x));
    return __fdividef(1.0f, 1.0f + __expf(-x));
}

// ---------------------------------------------------------------------------
// Generic tiled GEMM:
//   C[z][m][g] = act( sum_k A1[z][m][k]*W1[z][g][k] + sum_k A2[m][k]*W2[g][k]
//                     + bias1[g] )
// TRANSW: W element (g,k) lives at W[k*ldw + g]  (used for Ue_data precompute)
// WBF16:  W stored as bf16 (used for UH2 = Ud @ H^T)
// Requires: block rows (gridDim.y*64) and cols (gridDim.x*64) fully in-range;
// K may be arbitrary (masked loads).
// ---------------------------------------------------------------------------
template<bool WBF16, bool TRANSW, bool CBF16, bool RELU>
__global__ __launch_bounds__(256) void gemm_k(
    const float* __restrict__ A1, int lda1, long sA1z, int K1,
    const float* __restrict__ A2, int lda2, int K2,
    const void* __restrict__ W1v, int ldw1, long sW1z,
    const void* __restrict__ W2v, int ldw2,
    const float* __restrict__ bias1,
    void* __restrict__ Cv, int ldc, long sCz)
{
    __shared__ float As[32][68];   // [k][m], padded stride 68 (bank spread)
    __shared__ float Ws[32][68];   // [k][g]
    const int tid = threadIdx.x;
    const int z = blockIdx.z;
    const int m0 = blockIdx.y * 64;
    const int g0 = blockIdx.x * 64;
    const int tm = tid & 15, tn = tid >> 4;
    float acc[4][4];
#pragma unroll
    for (int i = 0; i < 4; ++i)
#pragma unroll
        for (int j = 0; j < 4; ++j) acc[i][j] = 0.0f;

    for (int phase = 0; phase < 2; ++phase) {
        const float* A = (phase == 0) ? (A1 + (long)z * sA1z) : A2;
        const int lda = (phase == 0) ? lda1 : lda2;
        const int K = (phase == 0) ? K1 : K2;
        const int ldw = (phase == 0) ? ldw1 : ldw2;
        const void* Wv = (phase == 0) ? W1v : W2v;
        const long woff = (phase == 0) ? (long)z * sW1z : 0;
        if (A == nullptr || Wv == nullptr || K <= 0) continue;

        for (int k0 = 0; k0 < K; k0 += 32) {
            const int rem = K - k0;
            {   // A tile -> As[k][m]
                const int tr0 = tid >> 3;
                const int tk = (tid & 7) * 4;
#pragma unroll
                for (int pass = 0; pass < 2; ++pass) {
                    const int m = tr0 + pass * 32;
                    const float* p = A + (long)(m0 + m) * lda + k0 + tk;
#pragma unroll
                    for (int j = 0; j < 4; ++j) {
                        float v = 0.0f;
                        if (tk + j < rem) v = p[j];
                        As[tk + j][m] = v;
                    }
                }
            }
            if constexpr (TRANSW) {
                const float* W = (const float*)Wv + woff;
                const int gq = (tid & 15) * 4;
                const int kr = tid >> 4;
#pragma unroll
                for (int pass = 0; pass < 2; ++pass) {
                    const int k = kr + pass * 16;
                    const float* p = W + (long)(k0 + k) * ldw + g0 + gq;
                    const bool ok = (k < rem);
#pragma unroll
                    for (int j = 0; j < 4; ++j) {
                        float v = 0.0f;
                        if (ok) v = p[j];
                        Ws[k][gq + j] = v;
                    }
                }
            } else if constexpr (WBF16) {
                const ushort_t* W = (const ushort_t*)Wv + woff;
                const int g = tid >> 2;
                const int tk = (tid & 3) * 8;
                const ushort_t* p = W + (long)(g0 + g) * ldw + k0 + tk;
#pragma unroll
                for (int j = 0; j < 8; ++j) {
                    float v = 0.0f;
                    if (tk + j < rem) v = bf2f(p[j]);
                    Ws[tk + j][g] = v;
                }
            } else {
                const float* W = (const float*)Wv + woff;
                const int tr0 = tid >> 3;
                const int tk = (tid & 7) * 4;
#pragma unroll
                for (int pass = 0; pass < 2; ++pass) {
                    const int g = tr0 + pass * 32;
                    const float* p = W + (long)(g0 + g) * ldw + k0 + tk;
#pragma unroll
                    for (int j = 0; j < 4; ++j) {
                        float v = 0.0f;
                        if (tk + j < rem) v = p[j];
                        Ws[tk + j][g] = v;
                    }
                }
            }
            __syncthreads();
#pragma unroll
            for (int kk = 0; kk < 32; ++kk) {
                const float4 av = *(const float4*)&As[kk][tm * 4];
                const float4 bv = *(const float4*)&Ws[kk][tn * 4];
                const float a[4] = {av.x, av.y, av.z, av.w};
                const float b[4] = {bv.x, bv.y, bv.z, bv.w};
#pragma unroll
                for (int i = 0; i < 4; ++i)
#pragma unroll
                    for (int j = 0; j < 4; ++j)
                        acc[i][j] = fmaf(a[i], b[j], acc[i][j]);
            }
            __syncthreads();
        }
    }
#pragma unroll
    for (int i = 0; i < 4; ++i) {
        const long m = m0 + tm * 4 + i;
#pragma unroll
        for (int j = 0; j < 4; ++j) {
            const int g = g0 + tn * 4 + j;
            float v = acc[i][j];
            if (bias1) v += bias1[g];
            if (RELU) v = fmaxf(v, 0.0f);
            if constexpr (CBF16)
                ((ushort_t*)Cv)[(long)z * sCz + m * ldc + g] = f2bf(v);
            else
                ((float*)Cv)[(long)z * sCz + m * ldc + g] = v;
        }
    }
}

// ---------------------------------------------------------------------------
// Fused LSTM gates GEMM + cell update.
// gates[b][g] = sum_k A1[b][k]*Wih[g][k] + sum_k h[b][k]*Whh[g][k] + bih[g]+bhh[g]
// with g = q*256 + bg, q in {i,f,g,o}. Block covers 64 b-rows x 16 bg-units
// (x 4 quadrants), so each thread owns all 4 gates of its (b,bg) pairs and can
// apply the nonlinearity. Writes h_out/c_out (other parity buffer) and
// optionally the bf16 H history at step t.
// ---------------------------------------------------------------------------
__global__ __launch_bounds__(256) void lstm_k(
    const float* __restrict__ A1, int lda1, int K1,
    const float* __restrict__ Wih, int ldw1,
    const float* __restrict__ hin,
    const float* __restrict__ Whh,
    const float* __restrict__ bih, const float* __restrict__ bhh,
    const float* __restrict__ cin,
    float* __restrict__ hout, float* __restrict__ cout,
    ushort_t* __restrict__ Hhist, int t)
{
    __shared__ float As[32][68];
    __shared__ float Ws[32][68];   // [k][col], col = r*4 + q  (r=unit, q=gate)
    const int tid = threadIdx.x;
    const int m0 = blockIdx.y * 64;
    const int bg0 = blockIdx.x * 16;
    const int tm = tid & 15, tn = tid >> 4;
    float acc[4][4];
#pragma unroll
    for (int i = 0; i < 4; ++i)
#pragma unroll
        for (int j = 0; j < 4; ++j) acc[i][j] = 0.0f;

    for (int phase = 0; phase < 2; ++phase) {
        const float* A = phase ? hin : A1;
        const int lda = phase ? 256 : lda1;
        const int K = phase ? 256 : K1;
        const float* W = phase ? Whh : Wih;
        const int ldw = phase ? 256 : ldw1;

        for (int k0 = 0; k0 < K; k0 += 32) {
            const int rem = K - k0;
            {   // A tile
                const int tr0 = tid >> 3;
                const int tk = (tid & 7) * 4;
#pragma unroll
                for (int pass = 0; pass < 2; ++pass) {
                    const int m = tr0 + pass * 32;
                    const float* p = A + (long)(m0 + m) * lda + k0 + tk;
#pragma unroll
                    for (int j = 0; j < 4; ++j) {
                        float v = 0.0f;
                        if (tk + j < rem) v = p[j];
                        As[tk + j][m] = v;
                    }
                }
            }
            {   // W tile with quadrant interleave
                const int tr0 = tid >> 3;
                const int tk = (tid & 7) * 4;
#pragma unroll
                for (int pass = 0; pass < 2; ++pass) {
                    const int tr = tr0 + pass * 32;     // 0..63
                    const int q = tr >> 4, r = tr & 15;
                    const int grow = q * 256 + bg0 + r;
                    const int col = r * 4 + q;
                    const float* p = W + (long)grow * ldw + k0 + tk;
#pragma unroll
                    for (int j = 0; j < 4; ++j) {
                        float v = 0.0f;
                        if (tk + j < rem) v = p[j];
                        Ws[tk + j][col] = v;
                    }
                }
            }
            __syncthreads();
#pragma unroll
            for (int kk = 0; kk < 32; ++kk) {
                const float4 av = *(const float4*)&As[kk][tm * 4];
                const float4 bv = *(const float4*)&Ws[kk][tn * 4];
                const float a[4] = {av.x, av.y, av.z, av.w};
                const float b[4] = {bv.x, bv.y, bv.z, bv.w};
#pragma unroll
                for (int i = 0; i < 4; ++i)
#pragma unroll
                    for (int j = 0; j < 4; ++j)
                        acc[i][j] = fmaf(a[i], b[j], acc[i][j]);
            }
            __syncthreads();
        }
    }
    // epilogue: acc[i][q] for b = m0+tm*4+i, unit bg = bg0+tn, gate q
    const int bg = bg0 + tn;
    const float b_i = bih[bg] + bhh[bg];
    const float b_f = bih[256 + bg] + bhh[256 + bg];
    const float b_g = bih[512 + bg] + bhh[512 + bg];
    const float b_o = bih[768 + bg] + bhh[768 + bg];
#pragma unroll
    for (int i = 0; i < 4; ++i) {
        const long b = m0 + tm * 4 + i;
        const float iv = sig_fast(acc[i][0] + b_i);
        const float fv = sig_fast(acc[i][1] + b_f);
        const float gv = tanh_fast(acc[i][2] + b_g);
        const float ov = sig_fast(acc[i][3] + b_o);
        const float cn = fv * cin[b * 256 + bg] + iv * gv;
        const float hn = ov * tanh_fast(cn);
        cout[b * 256 + bg] = cn;
        hout[b * 256 + bg] = hn;
        if (Hhist) Hhist[(b * 128 + t) * 256 + bg] = f2bf(hn);
    }
}

// ---------------------------------------------------------------------------
// Encoder input attention: score[b][n] = sum_s tanh(wq[b][s] + D[b][s][n])*ve[s]
// -> softmax over n -> x_tilde[b][n] = alpha * enc_data[b][t][n].
// One block per b, 128 threads (thread = n).
// ---------------------------------------------------------------------------
__global__ __launch_bounds__(128) void enc_attn_k(
    const ushort_t* __restrict__ D, const float* __restrict__ wq,
    const float* __restrict__ ve, const float* __restrict__ enc_data,
    float* __restrict__ xt, int t)
{
    const int b = blockIdx.x, n = threadIdx.x;
    __shared__ float wqs[128], ves[128], red[128];
    wqs[n] = wq[b * 128 + n];
    ves[n] = ve[n];
    __syncthreads();
    const ushort_t* Db = D + (long)b * (TT * NN);
    float acc = 0.0f;
#pragma unroll 4
    for (int s = 0; s < 128; ++s)
        acc += tanh_fast(wqs[s] + bf2f(Db[s * 128 + n])) * ves[s];
    // softmax over n
    red[n] = acc; __syncthreads();
    for (int o = 64; o > 0; o >>= 1) {
        if (n < o) red[n] = fmaxf(red[n], red[n + o]);
        __syncthreads();
    }
    const float mx = red[0]; __syncthreads();
    const float e = __expf(acc - mx);
    red[n] = e; __syncthreads();
    for (int o = 64; o > 0; o >>= 1) {
        if (n < o) red[n] += red[n + o];
        __syncthreads();
    }
    const float alpha = e * __fdividef(1.0f, red[0]);
    xt[b * 128 + n] = alpha * enc_data[((long)b * TT + t) * NN + n];
}

// ---------------------------------------------------------------------------
// Decoder temporal attention + context + y_tilde.
// score[b][t'] = sum_u tanh(wq[b][u] + UH2[b][u][t'])*vd[u] -> softmax over t'
// ctx[b][m] = sum_t beta[t]*H[b][t][m]
// y_tilde[b] = wt_b + wt_w[0]*dec_data[b][td] + sum_m wt_w[1+m]*ctx[b][m]
// One block per b, 128 threads (thread = t' for scores, 2 m's for ctx).
// ---------------------------------------------------------------------------
__global__ __launch_bounds__(128) void dec_attn_k(
    const ushort_t* __restrict__ UH2, const float* __restrict__ wqd,
    const float* __restrict__ vd, const ushort_t* __restrict__ Hb16,
    const float* __restrict__ dec_data, const float* __restrict__ wt_w,
    const float* __restrict__ wt_b,
    float* __restrict__ ctx, float* __restrict__ yt, int td, int compute_y)
{
    const int b = blockIdx.x, tt = threadIdx.x;
    __shared__ float wqs[256], vds[256], red[128], bs[128];
    wqs[tt] = wqd[b * 256 + tt];
    wqs[tt + 128] = wqd[b * 256 + tt + 128];
    vds[tt] = vd[tt];
    vds[tt + 128] = vd[tt + 128];
    __syncthreads();
    const ushort_t* Ub = UH2 + (long)b * (MM * TT);
    float acc = 0.0f;
#pragma unroll 4
    for (int u = 0; u < 256; ++u)
        acc += tanh_fast(wqs[u] + bf2f(Ub[u * 128 + tt])) * vds[u];
    // softmax over t'
    red[tt] = acc; __syncthreads();
    for (int o = 64; o > 0; o >>= 1) {
        if (tt < o) red[tt] = fmaxf(red[tt], red[tt + o]);
        __syncthreads();
    }
    const float mx = red[0]; __syncthreads();
    const float e = __expf(acc - mx);
    red[tt] = e; __syncthreads();
    for (int o = 64; o > 0; o >>= 1) {
        if (tt < o) red[tt] += red[tt + o];
        __syncthreads();
    }
    bs[tt] = e * __fdividef(1.0f, red[0]);
    __syncthreads();
    // ctx (each thread: m = tt and tt+128)
    const ushort_t* Hb = Hb16 + (long)b * (TT * MM);
    float c0 = 0.0f, c1 = 0.0f;
#pragma unroll 4
    for (int s = 0; s < 128; ++s) {
        const float bt = bs[s];
        c0 += bt * bf2f(Hb[s * 256 + tt]);
        c1 += bt * bf2f(Hb[s * 256 + tt + 128]);
    }
    ctx[b * 256 + tt] = c0;
    ctx[b * 256 + tt + 128] = c1;
    if (compute_y) {
        float part = c0 * wt_w[1 + tt] + c1 * wt_w[1 + tt + 128];
        __syncthreads();
        red[tt] = part; __syncthreads();
        for (int o = 64; o > 0; o >>= 1) {
            if (tt < o) red[tt] += red[tt + o];
            __syncthreads();
        }
        if (tt == 0)
            yt[b] = red[0] + wt_b[0] + wt_w[0] * dec_data[(long)b * TT + td];
    }
}

// out[b] = l2_b + sum_r l2_w[r] * l1out[b][r]
__global__ __launch_bounds__(256) void out_k(
    const float* __restrict__ l1o, const float* __restrict__ l2_w,
    const float* __restrict__ l2_b, float* __restrict__ out)
{
    const int b = blockIdx.x, r = threadIdx.x;
    __shared__ float red[256];
    red[r] = l1o[b * 256 + r] * l2_w[r];
    __syncthreads();
    for (int o = 128; o > 0; o >>= 1) {
        if (r < o) red[r] += red[r + o];
        __syncthreads();
    }
    if (r == 0) out[b] = red[0] + l2_b[0];
}

extern "C" void kernel_launch(void* const* d_in, const int* in_sizes, int n_in,
                              void* d_out, int out_size, void* d_ws, size_t ws_size,
                              hipStream_t stream)
{
    const float* enc_data = (const float*)d_in[0];
    const float* dec_data = (const float*)d_in[1];
    const float* enc_Wih  = (const float*)d_in[2];
    const float* enc_Whh  = (const float*)d_in[3];
    const float* enc_bih  = (const float*)d_in[4];
    const float* enc_bhh  = (const float*)d_in[5];
    const float* We   = (const float*)d_in[6];
    const float* Ue   = (const float*)d_in[7];
    const float* ve   = (const float*)d_in[8];
    const float* Wd   = (const float*)d_in[9];
    const float* Ud   = (const float*)d_in[10];
    const float* vd   = (const float*)d_in[11];
    const float* wt_w = (const float*)d_in[12];
    const float* wt_b = (const float*)d_in[13];
    const float* dec_Wih = (const float*)d_in[14];
    const float* dec_Whh = (const float*)d_in[15];
    const float* dec_bih = (const float*)d_in[16];
    const float* dec_bhh = (const float*)d_in[17];
    const float* l1_w = (const float*)d_in[18];
    const float* l1_b = (const float*)d_in[19];
    const float* l2_w = (const float*)d_in[20];
    const float* l2_b = (const float*)d_in[21];

    // workspace layout (~180 MB)
    ushort_t* Dbf  = (ushort_t*)d_ws;                        // D[b][s][n]  bf16
    ushort_t* Hbf  = Dbf + (long)BATCH * TT * NN;            // H[b][t][m]  bf16
    ushort_t* UHbf = Hbf + (long)BATCH * TT * MM;            // UH2[b][u][t] bf16
    float* states  = (float*)(UHbf + (long)BATCH * MM * TT); // [h0 c0 d0 s0 h1 c1 d1 s1]
    const long SS = (long)BATCH * 256;
    float* wqb = states + 8 * SS;       // B x 256 (used as 128 or 256 wide)
    float* xt  = wqb + SS;              // B x 128
    float* ctx = xt + (long)BATCH * 128;
    float* yt  = ctx + SS;              // B
    float* l1o = yt + BATCH;            // B x 256

    // zero initial states (parity 0)
    hipMemsetAsync(states, 0, (size_t)4 * SS * sizeof(float), stream);

    // D[b][s][n] = sum_t Ue[s][t] * enc_data[b][t][n]
    gemm_k<false, true, true, false><<<dim3(NN / 64, TT / 64, BATCH), 256, 0, stream>>>(
        Ue, TT, 0, TT,
        nullptr, 0, 0,
        enc_data, NN, (long)TT * NN,
        nullptr, 0,
        nullptr,
        Dbf, NN, (long)TT * NN);

    // ---- encoder ----
    for (int t = 0; t < 128; ++t) {
        const int p = t & 1;
        float* h  = states + (p * 4 + 0) * SS;
        float* c  = states + (p * 4 + 1) * SS;
        float* hn = states + ((1 - p) * 4 + 0) * SS;
        float* cn = states + ((1 - p) * 4 + 1) * SS;
        // wq = [h,c] @ We^T   (B x 128)
        gemm_k<false, false, false, false><<<dim3(2, 16, 1), 256, 0, stream>>>(
            h, 256, 0, 256, c, 256, 256,
            We, 512, 0, We + 256, 512,
            nullptr, wqb, 128, 0);
        enc_attn_k<<<dim3(BATCH), 128, 0, stream>>>(Dbf, wqb, ve, enc_data, xt, t);
        lstm_k<<<dim3(16, 16), 256, 0, stream>>>(
            xt, 128, 128, enc_Wih, 128,
            h, enc_Whh, enc_bih, enc_bhh, c,
            hn, cn, Hbf, t);
    }

    // UH2[b][u][t'] = sum_m Ud[u][m] * H[b][t'][m]
    gemm_k<true, false, true, false><<<dim3(TT / 64, MM / 64, BATCH), 256, 0, stream>>>(
        Ud, 256, 0, 256,
        nullptr, 0, 0,
        Hbf, 256, (long)TT * MM,
        nullptr, 0,
        nullptr,
        UHbf, TT, (long)MM * TT);

    // ---- decoder ----
    for (int td = 0; td < 127; ++td) {
        const int p = td & 1;
        float* dh = states + (p * 4 + 2) * SS;
        float* sc = states + (p * 4 + 3) * SS;
        float* dn = states + ((1 - p) * 4 + 2) * SS;
        float* sn = states + ((1 - p) * 4 + 3) * SS;
        // wq = [d,s] @ Wd^T   (B x 256)
        gemm_k<false, false, false, false><<<dim3(4, 16, 1), 256, 0, stream>>>(
            dh, 256, 0, 256, sc, 256, 256,
            Wd, 512, 0, Wd + 256, 512,
            nullptr, wqb, 256, 0);
        dec_attn_k<<<dim3(BATCH), 128, 0, stream>>>(
            UHbf, wqb, vd, Hbf, dec_data, wt_w, wt_b, ctx, yt, td, 1);
        lstm_k<<<dim3(16, 16), 256, 0, stream>>>(
            yt, 1, 1, dec_Wih, 1,
            dh, dec_Whh, dec_bih, dec_bhh, sc,
            dn, sn, nullptr, 0);
    }

    // ---- final attention + MLP ----
    {
        float* dh = states + (1 * 4 + 2) * SS;   // parity after 127 steps
        float* sc = states + (1 * 4 + 3) * SS;
        gemm_k<false, false, false, false><<<dim3(4, 16, 1), 256, 0, stream>>>(
            dh, 256, 0, 256, sc, 256, 256,
            Wd, 512, 0, Wd + 256, 512,
            nullptr, wqb, 256, 0);
        dec_attn_k<<<dim3(BATCH), 128, 0, stream>>>(
            UHbf, wqb, vd, Hbf, dec_data, wt_w, wt_b, ctx, yt, 0, 0);
        // l1out = relu([d, ctx] @ l1_w^T + l1_b)
        gemm_k<false, false, false, true><<<dim3(4, 16, 1), 256, 0, stream>>>(
            dh, 256, 0, 256, ctx, 256, 256,
            l1_w, 512, 0, l1_w + 256, 512,
            l1_b, l1o, 256, 0);
        out_k<<<dim3(BATCH), 256, 0, stream>>>(l1o, l2_w, l2_b, (float*)d_out);
    }
}

// Round 2
// 18875.784 us; speedup vs baseline: 1.6470x; 1.6470x over previous
//
#include <hip/hip_runtime.h>

typedef unsigned short ushort_t;

static constexpr int BATCH = 1024;
static constexpr int TT = 128;   // T
static constexpr int NN = 128;   // N
static constexpr int MM = 256;   // M == P

__device__ __forceinline__ float bf2f(ushort_t u) {
    union { unsigned int i; float f; } v;
    v.i = ((unsigned int)u) << 16;
    return v.f;
}
__device__ __forceinline__ ushort_t f2bf(float f) {
    union { unsigned int i; float f; } v;
    v.f = f;
    unsigned int i = v.i;
    return (ushort_t)((i + 0x7FFFu + ((i >> 16) & 1u)) >> 16);
}
__device__ __forceinline__ float tanh_fast(float x) {
    x = fminf(9.0f, fmaxf(-9.0f, x));
    float e = __expf(2.0f * x);
    return 1.0f - __fdividef(2.0f, e + 1.0f);
}
__device__ __forceinline__ float sig_fast(float x) {
    x = fminf(30.0f, fmaxf(-30.0f, x));
    return __fdividef(1.0f, 1.0f + __expf(-x));
}

// ---------------------------------------------------------------------------
// Generic tiled GEMM (verified round 1) — used only for the two one-time
// precomputes: D = Ue_data (TRANSW path) and UH2 (WBF16 path).
// ---------------------------------------------------------------------------
template<bool WBF16, bool TRANSW, bool CBF16, bool RELU>
__global__ __launch_bounds__(256) void gemm_k(
    const float* __restrict__ A1, int lda1, long sA1z, int K1,
    const float* __restrict__ A2, int lda2, int K2,
    const void* __restrict__ W1v, int ldw1, long sW1z,
    const void* __restrict__ W2v, int ldw2,
    const float* __restrict__ bias1,
    void* __restrict__ Cv, int ldc, long sCz)
{
    __shared__ float As[32][68];
    __shared__ float Ws[32][68];
    const int tid = threadIdx.x;
    const int z = blockIdx.z;
    const int m0 = blockIdx.y * 64;
    const int g0 = blockIdx.x * 64;
    const int tm = tid & 15, tn = tid >> 4;
    float acc[4][4];
#pragma unroll
    for (int i = 0; i < 4; ++i)
#pragma unroll
        for (int j = 0; j < 4; ++j) acc[i][j] = 0.0f;

    for (int phase = 0; phase < 2; ++phase) {
        const float* A = (phase == 0) ? (A1 + (long)z * sA1z) : A2;
        const int lda = (phase == 0) ? lda1 : lda2;
        const int K = (phase == 0) ? K1 : K2;
        const int ldw = (phase == 0) ? ldw1 : ldw2;
        const void* Wv = (phase == 0) ? W1v : W2v;
        const long woff = (phase == 0) ? (long)z * sW1z : 0;
        if (A == nullptr || Wv == nullptr || K <= 0) continue;

        for (int k0 = 0; k0 < K; k0 += 32) {
            const int rem = K - k0;
            {
                const int tr0 = tid >> 3;
                const int tk = (tid & 7) * 4;
#pragma unroll
                for (int pass = 0; pass < 2; ++pass) {
                    const int m = tr0 + pass * 32;
                    const float* p = A + (long)(m0 + m) * lda + k0 + tk;
#pragma unroll
                    for (int j = 0; j < 4; ++j) {
                        float v = 0.0f;
                        if (tk + j < rem) v = p[j];
                        As[tk + j][m] = v;
                    }
                }
            }
            if constexpr (TRANSW) {
                const float* W = (const float*)Wv + woff;
                const int gq = (tid & 15) * 4;
                const int kr = tid >> 4;
#pragma unroll
                for (int pass = 0; pass < 2; ++pass) {
                    const int k = kr + pass * 16;
                    const float* p = W + (long)(k0 + k) * ldw + g0 + gq;
                    const bool ok = (k < rem);
#pragma unroll
                    for (int j = 0; j < 4; ++j) {
                        float v = 0.0f;
                        if (ok) v = p[j];
                        Ws[k][gq + j] = v;
                    }
                }
            } else if constexpr (WBF16) {
                const ushort_t* W = (const ushort_t*)Wv + woff;
                const int g = tid >> 2;
                const int tk = (tid & 3) * 8;
                const ushort_t* p = W + (long)(g0 + g) * ldw + k0 + tk;
#pragma unroll
                for (int j = 0; j < 8; ++j) {
                    float v = 0.0f;
                    if (tk + j < rem) v = bf2f(p[j]);
                    Ws[tk + j][g] = v;
                }
            } else {
                const float* W = (const float*)Wv + woff;
                const int tr0 = tid >> 3;
                const int tk = (tid & 7) * 4;
#pragma unroll
                for (int pass = 0; pass < 2; ++pass) {
                    const int g = tr0 + pass * 32;
                    const float* p = W + (long)(g0 + g) * ldw + k0 + tk;
#pragma unroll
                    for (int j = 0; j < 4; ++j) {
                        float v = 0.0f;
                        if (tk + j < rem) v = p[j];
                        Ws[tk + j][g] = v;
                    }
                }
            }
            __syncthreads();
#pragma unroll
            for (int kk = 0; kk < 32; ++kk) {
                const float4 av = *(const float4*)&As[kk][tm * 4];
                const float4 bv = *(const float4*)&Ws[kk][tn * 4];
                const float a[4] = {av.x, av.y, av.z, av.w};
                const float b[4] = {bv.x, bv.y, bv.z, bv.w};
#pragma unroll
                for (int i = 0; i < 4; ++i)
#pragma unroll
                    for (int j = 0; j < 4; ++j)
                        acc[i][j] = fmaf(a[i], b[j], acc[i][j]);
            }
            __syncthreads();
        }
    }
#pragma unroll
    for (int i = 0; i < 4; ++i) {
        const long m = m0 + tm * 4 + i;
#pragma unroll
        for (int j = 0; j < 4; ++j) {
            const int g = g0 + tn * 4 + j;
            float v = acc[i][j];
            if (bias1) v += bias1[g];
            if (RELU) v = fmaxf(v, 0.0f);
            if constexpr (CBF16)
                ((ushort_t*)Cv)[(long)z * sCz + m * ldc + g] = f2bf(v);
            else
                ((float*)Cv)[(long)z * sCz + m * ldc + g] = v;
        }
    }
}

// ---------------------------------------------------------------------------
// Weight prep: gate weights -> [k][u*4+q] fp32 (coalesced dwordx4 per thread);
// attention/query/MLP weights -> transposed [k][out].
// ---------------------------------------------------------------------------
__global__ void prep_encw_k(const float* __restrict__ Wih, const float* __restrict__ Whh,
                            float* __restrict__ dst) {
    int i = blockIdx.x * 256 + threadIdx.x;
    if (i >= 384 * 1024) return;
    int k = i >> 10, col = i & 1023, u = col >> 2, q = col & 3, g = q * 256 + u;
    dst[i] = (k < 128) ? Wih[g * 128 + k] : Whh[g * 256 + (k - 128)];
}

__global__ void prep_decw_k(const float* __restrict__ Wih, const float* __restrict__ Whh,
                            float* __restrict__ dst) {
    int i = blockIdx.x * 256 + threadIdx.x;
    if (i >= 257 * 1024) return;
    int k = i >> 10, col = i & 1023, u = col >> 2, q = col & 3, g = q * 256 + u;
    dst[i] = (k == 0) ? Wih[g] : Whh[g * 256 + (k - 1)];
}

// src is R x C, dst is C x R: dst[c*R + r] = src[r*C + c]
__global__ void transpose_k(const float* __restrict__ src, float* __restrict__ dst,
                            int R, int C) {
    int i = blockIdx.x * 256 + threadIdx.x;
    if (i < R * C) { int r = i / C, c = i - r * C; dst[c * R + r] = src[i]; }
}

// ---------------------------------------------------------------------------
// Persistent encoder: 256 blocks x 256 threads; block owns 4 batch rows for
// all 128 time steps. h/c live in LDS; thread tid owns LSTM unit u=tid.
// ---------------------------------------------------------------------------
__global__ __launch_bounds__(256) void enc_persist(
    const float* __restrict__ enc_data,   // [1024][128][128]
    const ushort_t* __restrict__ D,       // [1024][128][128] bf16
    const float* __restrict__ WeT,        // [512][128]
    const float* __restrict__ ve,         // [128]
    const float* __restrict__ WencT,      // [384][1024]
    const float* __restrict__ bih, const float* __restrict__ bhh,
    ushort_t* __restrict__ Hbf)           // [1024][128][256] bf16
{
    const int tid = threadIdx.x;
    const int b0 = blockIdx.x * 4;
    __shared__ __align__(16) float hs[256][4];
    __shared__ __align__(16) float cs[256][4];
    __shared__ __align__(16) float xt[128][4];
    __shared__ __align__(16) float wqp4[4][128][4];
    __shared__ __align__(16) float wqs[128][4];
    __shared__ float scp[2][4][128];
    __shared__ float ves[128];

    if (tid < 128) ves[tid] = ve[tid];
    {
        const float4 z = make_float4(0.f, 0.f, 0.f, 0.f);
        *(float4*)hs[tid] = z;
        *(float4*)cs[tid] = z;
    }
    const float b_i = bih[tid] + bhh[tid];
    const float b_f = bih[256 + tid] + bhh[256 + tid];
    const float b_g = bih[512 + tid] + bhh[512 + tid];
    const float b_o = bih[768 + tid] + bhh[768 + tid];
    __syncthreads();

    const int kq = tid >> 6, sb = tid & 63;          // wq mapping
    const float* wq_w = WeT + kq * 128 * 128;
    const int n_ = tid & 127, sh = tid >> 7;         // scores mapping
    const float* gw = WencT + tid * 4;               // gates weight base

    for (int t = 0; t < 128; ++t) {
        // ---- wq partials: q=[h,c], k-split 4; thread covers s=sb, sb+64 ----
        {
            const float* qb = (kq < 2) ? &hs[kq * 128][0] : &cs[(kq - 2) * 128][0];
            float a0 = 0, a1 = 0, a2 = 0, a3 = 0;
            float c0 = 0, c1 = 0, c2 = 0, c3 = 0;
#pragma unroll 4
            for (int kk = 0; kk < 128; ++kk) {
                const float4 q = *(const float4*)(qb + kk * 4);
                const float w0 = wq_w[kk * 128 + sb];
                const float w1 = wq_w[kk * 128 + sb + 64];
                a0 = fmaf(q.x, w0, a0); a1 = fmaf(q.y, w0, a1);
                a2 = fmaf(q.z, w0, a2); a3 = fmaf(q.w, w0, a3);
                c0 = fmaf(q.x, w1, c0); c1 = fmaf(q.y, w1, c1);
                c2 = fmaf(q.z, w1, c2); c3 = fmaf(q.w, w1, c3);
            }
            *(float4*)wqp4[kq][sb] = make_float4(a0, a1, a2, a3);
            *(float4*)wqp4[kq][sb + 64] = make_float4(c0, c1, c2, c3);
        }
        __syncthreads();
        if (tid < 128) {
            const float4 p0 = *(const float4*)wqp4[0][tid];
            const float4 p1 = *(const float4*)wqp4[1][tid];
            const float4 p2 = *(const float4*)wqp4[2][tid];
            const float4 p3 = *(const float4*)wqp4[3][tid];
            *(float4*)wqs[tid] = make_float4(p0.x + p1.x + p2.x + p3.x,
                                             p0.y + p1.y + p2.y + p3.y,
                                             p0.z + p1.z + p2.z + p3.z,
                                             p0.w + p1.w + p2.w + p3.w);
        }
        __syncthreads();
        // ---- attention scores: thread = (n, s-half) ----
        {
            const ushort_t* Dp = D + (long)b0 * 16384 + (sh * 64) * 128 + n_;
            float a0 = 0, a1 = 0, a2 = 0, a3 = 0;
#pragma unroll 2
            for (int s = 0; s < 64; ++s) {
                const int ss = sh * 64 + s;
                const float4 wq4 = *(const float4*)wqs[ss];
                const float vv = ves[ss];
                const ushort_t* dp = Dp + s * 128;
                a0 = fmaf(tanh_fast(wq4.x + bf2f(dp[0])),     vv, a0);
                a1 = fmaf(tanh_fast(wq4.y + bf2f(dp[16384])), vv, a1);
                a2 = fmaf(tanh_fast(wq4.z + bf2f(dp[32768])), vv, a2);
                a3 = fmaf(tanh_fast(wq4.w + bf2f(dp[49152])), vv, a3);
            }
            scp[sh][0][n_] = a0; scp[sh][1][n_] = a1;
            scp[sh][2][n_] = a2; scp[sh][3][n_] = a3;
        }
        __syncthreads();
        // ---- softmax + x_tilde: wave w handles row w ----
        {
            const int w = tid >> 6, lane = tid & 63;
            const float s0 = scp[0][w][lane] + scp[1][w][lane];
            const float s1 = scp[0][w][lane + 64] + scp[1][w][lane + 64];
            float mx = fmaxf(s0, s1);
            for (int o = 32; o > 0; o >>= 1) mx = fmaxf(mx, __shfl_xor(mx, o, 64));
            const float e0 = __expf(s0 - mx), e1 = __expf(s1 - mx);
            float sm = e0 + e1;
            for (int o = 32; o > 0; o >>= 1) sm += __shfl_xor(sm, o, 64);
            const float inv = __fdividef(1.0f, sm);
            const float* xp = enc_data + ((long)(b0 + w) * 128 + t) * 128;
            xt[lane][w] = e0 * inv * xp[lane];
            xt[lane + 64][w] = e1 * inv * xp[lane + 64];
        }
        __syncthreads();
        // ---- gates: thread owns unit u=tid, 4 gates x 4 rows ----
        float acc[4][4];
#pragma unroll
        for (int q = 0; q < 4; ++q)
#pragma unroll
            for (int r = 0; r < 4; ++r) acc[q][r] = 0.0f;
        {
#pragma unroll 8
            for (int k = 0; k < 128; ++k) {
                const float4 wv = *(const float4*)(gw + (long)k * 1024);
                const float4 xv = *(const float4*)xt[k];
                const float wa[4] = {wv.x, wv.y, wv.z, wv.w};
                const float xa[4] = {xv.x, xv.y, xv.z, xv.w};
#pragma unroll
                for (int q = 0; q < 4; ++q)
#pragma unroll
                    for (int r = 0; r < 4; ++r)
                        acc[q][r] = fmaf(wa[q], xa[r], acc[q][r]);
            }
            const float* gw2 = gw + 128 * 1024;
#pragma unroll 8
            for (int k = 0; k < 256; ++k) {
                const float4 wv = *(const float4*)(gw2 + (long)k * 1024);
                const float4 xv = *(const float4*)hs[k];
                const float wa[4] = {wv.x, wv.y, wv.z, wv.w};
                const float xa[4] = {xv.x, xv.y, xv.z, xv.w};
#pragma unroll
                for (int q = 0; q < 4; ++q)
#pragma unroll
                    for (int r = 0; r < 4; ++r)
                        acc[q][r] = fmaf(wa[q], xa[r], acc[q][r]);
            }
        }
        __syncthreads();   // all reads of hs/xt complete before state update
#pragma unroll
        for (int r = 0; r < 4; ++r) {
            const float iv = sig_fast(acc[0][r] + b_i);
            const float fv = sig_fast(acc[1][r] + b_f);
            const float gv = tanh_fast(acc[2][r] + b_g);
            const float ov = sig_fast(acc[3][r] + b_o);
            const float cn = fv * cs[tid][r] + iv * gv;
            const float hn = ov * tanh_fast(cn);
            cs[tid][r] = cn;
            hs[tid][r] = hn;
            Hbf[((long)(b0 + r) * 128 + t) * 256 + tid] = f2bf(hn);
        }
        __syncthreads();
    }
}

// ---------------------------------------------------------------------------
// Persistent decoder + final attention + MLP. Same block structure.
// Thread tid owns unit u=tid. td=127 iteration computes the final attn ctx
// only, then the fused l1/l2 epilogue writes out[b].
// ---------------------------------------------------------------------------
__global__ __launch_bounds__(256) void dec_persist(
    const float* __restrict__ dec_data,   // [1024][128]
    const ushort_t* __restrict__ UH2,     // [1024][256][128] bf16
    const ushort_t* __restrict__ Hb,      // [1024][128][256] bf16
    const float* __restrict__ WdT,        // [512][256]
    const float* __restrict__ vd,         // [256]
    const float* __restrict__ WdecT,      // [257][1024]
    const float* __restrict__ bih, const float* __restrict__ bhh,
    const float* __restrict__ wt_w, const float* __restrict__ wt_b,
    const float* __restrict__ l1T,        // [512][256]
    const float* __restrict__ l1_b,
    const float* __restrict__ l2_w, const float* __restrict__ l2_b,
    float* __restrict__ out)
{
    const int tid = threadIdx.x;
    const int b0 = blockIdx.x * 4;
    __shared__ __align__(16) float ds4[256][4];
    __shared__ __align__(16) float ss4[256][4];
    __shared__ __align__(16) float wqp4[4][256][4];
    __shared__ __align__(16) float wqs[256][4];
    __shared__ float scp[2][4][128];
    __shared__ __align__(16) float beta[128][4];
    __shared__ __align__(16) float ctx4[256][4];
    __shared__ __align__(16) float o14[256][4];
    __shared__ float vds[256];
    __shared__ float wt1s[256];
    __shared__ float l2s[256];
    __shared__ __align__(16) float yts[4];

    vds[tid] = vd[tid];
    wt1s[tid] = wt_w[1 + tid];
    l2s[tid] = l2_w[tid];
    {
        const float4 z = make_float4(0.f, 0.f, 0.f, 0.f);
        *(float4*)ds4[tid] = z;
        *(float4*)ss4[tid] = z;
    }
    const float b_i = bih[tid] + bhh[tid];
    const float b_f = bih[256 + tid] + bhh[256 + tid];
    const float b_g = bih[512 + tid] + bhh[512 + tid];
    const float b_o = bih[768 + tid] + bhh[768 + tid];
    __syncthreads();

    const int kq = tid >> 6, mb = tid & 63;   // wq mapping: 4 m's per thread
    const float* wq_w = WdT + kq * 128 * 256;
    const int tp = tid & 127, uh = tid >> 7;  // scores mapping
    const float* gw = WdecT + tid * 4;

    for (int td = 0; td < 128; ++td) {
        // ---- wq partials: q=[d,s], k-split 4, thread covers m=mb+{0,64,128,192}
        {
            const float* qb = (kq < 2) ? &ds4[kq * 128][0] : &ss4[(kq - 2) * 128][0];
            float a[4][4];
#pragma unroll
            for (int mj = 0; mj < 4; ++mj)
#pragma unroll
                for (int r = 0; r < 4; ++r) a[mj][r] = 0.0f;
#pragma unroll 2
            for (int kk = 0; kk < 128; ++kk) {
                const float4 q = *(const float4*)(qb + kk * 4);
                const float qa[4] = {q.x, q.y, q.z, q.w};
#pragma unroll
                for (int mj = 0; mj < 4; ++mj) {
                    const float w = wq_w[kk * 256 + mb + mj * 64];
#pragma unroll
                    for (int r = 0; r < 4; ++r)
                        a[mj][r] = fmaf(qa[r], w, a[mj][r]);
                }
            }
#pragma unroll
            for (int mj = 0; mj < 4; ++mj)
                *(float4*)wqp4[kq][mb + mj * 64] =
                    make_float4(a[mj][0], a[mj][1], a[mj][2], a[mj][3]);
        }
        __syncthreads();
        {
            const float4 p0 = *(const float4*)wqp4[0][tid];
            const float4 p1 = *(const float4*)wqp4[1][tid];
            const float4 p2 = *(const float4*)wqp4[2][tid];
            const float4 p3 = *(const float4*)wqp4[3][tid];
            *(float4*)wqs[tid] = make_float4(p0.x + p1.x + p2.x + p3.x,
                                             p0.y + p1.y + p2.y + p3.y,
                                             p0.z + p1.z + p2.z + p3.z,
                                             p0.w + p1.w + p2.w + p3.w);
        }
        __syncthreads();
        // ---- temporal attention scores: thread = (t', u-half) ----
        {
            const ushort_t* up = UH2 + (long)b0 * 32768 + (uh * 128) * 128 + tp;
            float a0 = 0, a1 = 0, a2 = 0, a3 = 0;
#pragma unroll 2
            for (int u = 0; u < 128; ++u) {
                const int uu = uh * 128 + u;
                const float4 wq4 = *(const float4*)wqs[uu];
                const float vv = vds[uu];
                const ushort_t* p = up + u * 128;
                a0 = fmaf(tanh_fast(wq4.x + bf2f(p[0])),     vv, a0);
                a1 = fmaf(tanh_fast(wq4.y + bf2f(p[32768])), vv, a1);
                a2 = fmaf(tanh_fast(wq4.z + bf2f(p[65536])), vv, a2);
                a3 = fmaf(tanh_fast(wq4.w + bf2f(p[98304])), vv, a3);
            }
            scp[uh][0][tp] = a0; scp[uh][1][tp] = a1;
            scp[uh][2][tp] = a2; scp[uh][3][tp] = a3;
        }
        __syncthreads();
        // ---- softmax -> beta: wave w = row w ----
        {
            const int w = tid >> 6, lane = tid & 63;
            const float s0 = scp[0][w][lane] + scp[1][w][lane];
            const float s1 = scp[0][w][lane + 64] + scp[1][w][lane + 64];
            float mx = fmaxf(s0, s1);
            for (int o = 32; o > 0; o >>= 1) mx = fmaxf(mx, __shfl_xor(mx, o, 64));
            const float e0 = __expf(s0 - mx), e1 = __expf(s1 - mx);
            float sm = e0 + e1;
            for (int o = 32; o > 0; o >>= 1) sm += __shfl_xor(sm, o, 64);
            const float inv = __fdividef(1.0f, sm);
            beta[lane][w] = e0 * inv;
            beta[lane + 64][w] = e1 * inv;
        }
        __syncthreads();
        // ---- ctx: thread m = tid ----
        {
            const ushort_t* hp = Hb + (long)b0 * 32768 + tid;
            float c0 = 0, c1 = 0, c2 = 0, c3 = 0;
#pragma unroll 4
            for (int s = 0; s < 128; ++s) {
                const float4 bt = *(const float4*)beta[s];
                const ushort_t* p = hp + s * 256;
                c0 = fmaf(bt.x, bf2f(p[0]),     c0);
                c1 = fmaf(bt.y, bf2f(p[32768]), c1);
                c2 = fmaf(bt.z, bf2f(p[65536]), c2);
                c3 = fmaf(bt.w, bf2f(p[98304]), c3);
            }
            *(float4*)ctx4[tid] = make_float4(c0, c1, c2, c3);
        }
        __syncthreads();
        if (td == 127) break;     // final ctx computed with final (d,s)
        // ---- y_tilde: wave w = row w ----
        {
            const int w = tid >> 6, lane = tid & 63;
            float s = ctx4[lane][w] * wt1s[lane]
                    + ctx4[lane + 64][w] * wt1s[lane + 64]
                    + ctx4[lane + 128][w] * wt1s[lane + 128]
                    + ctx4[lane + 192][w] * wt1s[lane + 192];
            for (int o = 32; o > 0; o >>= 1) s += __shfl_xor(s, o, 64);
            if (lane == 0)
                yts[w] = s + wt_b[0] + wt_w[0] * dec_data[(long)(b0 + w) * 128 + td];
        }
        __syncthreads();
        // ---- gates (K = 1 + 256) ----
        float acc[4][4];
        {
            const float4 wv0 = *(const float4*)gw;      // WdecT row k=0
            const float4 y4 = *(const float4*)yts;
            const float wa0[4] = {wv0.x, wv0.y, wv0.z, wv0.w};
            const float ya[4] = {y4.x, y4.y, y4.z, y4.w};
#pragma unroll
            for (int q = 0; q < 4; ++q)
#pragma unroll
                for (int r = 0; r < 4; ++r) acc[q][r] = wa0[q] * ya[r];
            const float* gw2 = gw + 1024;
#pragma unroll 8
            for (int k = 0; k < 256; ++k) {
                const float4 wv = *(const float4*)(gw2 + (long)k * 1024);
                const float4 xv = *(const float4*)ds4[k];
                const float wa[4] = {wv.x, wv.y, wv.z, wv.w};
                const float xa[4] = {xv.x, xv.y, xv.z, xv.w};
#pragma unroll
                for (int q = 0; q < 4; ++q)
#pragma unroll
                    for (int r = 0; r < 4; ++r)
                        acc[q][r] = fmaf(wa[q], xa[r], acc[q][r]);
            }
        }
        __syncthreads();
#pragma unroll
        for (int r = 0; r < 4; ++r) {
            const float iv = sig_fast(acc[0][r] + b_i);
            const float fv = sig_fast(acc[1][r] + b_f);
            const float gv = tanh_fast(acc[2][r] + b_g);
            const float ov = sig_fast(acc[3][r] + b_o);
            const float sn = fv * ss4[tid][r] + iv * gv;
            const float dn = ov * tanh_fast(sn);
            ss4[tid][r] = sn;
            ds4[tid][r] = dn;
        }
        __syncthreads();
    }
    // ---- final MLP: l1 (thread j = tid), then l2 wave-reduce per row ----
    {
        float a0 = 0, a1 = 0, a2 = 0, a3 = 0;
#pragma unroll 4
        for (int k = 0; k < 256; ++k) {
            const float w = l1T[k * 256 + tid];
            const float4 q = *(const float4*)ds4[k];
            a0 = fmaf(q.x, w, a0); a1 = fmaf(q.y, w, a1);
            a2 = fmaf(q.z, w, a2); a3 = fmaf(q.w, w, a3);
        }
#pragma unroll 4
        for (int k = 0; k < 256; ++k) {
            const float w = l1T[(256 + k) * 256 + tid];
            const float4 q = *(const float4*)ctx4[k];
            a0 = fmaf(q.x, w, a0); a1 = fmaf(q.y, w, a1);
            a2 = fmaf(q.z, w, a2); a3 = fmaf(q.w, w, a3);
        }
        const float bb = l1_b[tid];
        *(float4*)o14[tid] = make_float4(fmaxf(a0 + bb, 0.f), fmaxf(a1 + bb, 0.f),
                                         fmaxf(a2 + bb, 0.f), fmaxf(a3 + bb, 0.f));
    }
    __syncthreads();
    {
        const int w = tid >> 6, lane = tid & 63;
        float s = o14[lane][w] * l2s[lane]
                + o14[lane + 64][w] * l2s[lane + 64]
                + o14[lane + 128][w] * l2s[lane + 128]
                + o14[lane + 192][w] * l2s[lane + 192];
        for (int o = 32; o > 0; o >>= 1) s += __shfl_xor(s, o, 64);
        if (lane == 0) out[b0 + w] = s + l2_b[0];
    }
}

extern "C" void kernel_launch(void* const* d_in, const int* in_sizes, int n_in,
                              void* d_out, int out_size, void* d_ws, size_t ws_size,
                              hipStream_t stream)
{
    const float* enc_data = (const float*)d_in[0];
    const float* dec_data = (const float*)d_in[1];
    const float* enc_Wih  = (const float*)d_in[2];
    const float* enc_Whh  = (const float*)d_in[3];
    const float* enc_bih  = (const float*)d_in[4];
    const float* enc_bhh  = (const float*)d_in[5];
    const float* We   = (const float*)d_in[6];
    const float* Ue   = (const float*)d_in[7];
    const float* ve   = (const float*)d_in[8];
    const float* Wd   = (const float*)d_in[9];
    const float* Ud   = (const float*)d_in[10];
    const float* vd   = (const float*)d_in[11];
    const float* wt_w = (const float*)d_in[12];
    const float* wt_b = (const float*)d_in[13];
    const float* dec_Wih = (const float*)d_in[14];
    const float* dec_Whh = (const float*)d_in[15];
    const float* dec_bih = (const float*)d_in[16];
    const float* dec_bhh = (const float*)d_in[17];
    const float* l1_w = (const float*)d_in[18];
    const float* l1_b = (const float*)d_in[19];
    const float* l2_w = (const float*)d_in[20];
    const float* l2_b = (const float*)d_in[21];

    // ---- workspace layout (~171 MB) ----
    ushort_t* Dbf  = (ushort_t*)d_ws;                         // 32 MB
    ushort_t* Hbf  = Dbf + (long)BATCH * TT * NN;             // 64 MB
    ushort_t* UHbf = Hbf + (long)BATCH * TT * MM;             // 64 MB
    float* WencT = (float*)(UHbf + (long)BATCH * MM * TT);    // 384*1024
    float* WdecT = WencT + 384 * 1024;                        // 257*1024
    float* WeT   = WdecT + 257 * 1024;                        // 512*128
    float* WdT   = WeT + 512 * 128;                           // 512*256
    float* l1T   = WdT + 512 * 256;                           // 512*256

    // ---- weight prep (cheap, every call; graph-safe) ----
    prep_encw_k<<<1536, 256, 0, stream>>>(enc_Wih, enc_Whh, WencT);
    prep_decw_k<<<1028, 256, 0, stream>>>(dec_Wih, dec_Whh, WdecT);
    transpose_k<<<(128 * 512 + 255) / 256, 256, 0, stream>>>(We, WeT, 128, 512);
    transpose_k<<<(256 * 512 + 255) / 256, 256, 0, stream>>>(Wd, WdT, 256, 512);
    transpose_k<<<(256 * 512 + 255) / 256, 256, 0, stream>>>(l1_w, l1T, 256, 512);

    // D[b][s][n] = sum_t Ue[s][t] * enc_data[b][t][n]
    gemm_k<false, true, true, false><<<dim3(NN / 64, TT / 64, BATCH), 256, 0, stream>>>(
        Ue, TT, 0, TT,
        nullptr, 0, 0,
        enc_data, NN, (long)TT * NN,
        nullptr, 0,
        nullptr,
        Dbf, NN, (long)TT * NN);

    // ---- full encoder (persistent) ----
    enc_persist<<<256, 256, 0, stream>>>(enc_data, Dbf, WeT, ve, WencT,
                                         enc_bih, enc_bhh, Hbf);

    // UH2[b][u][t'] = sum_m Ud[u][m] * H[b][t'][m]
    gemm_k<true, false, true, false><<<dim3(TT / 64, MM / 64, BATCH), 256, 0, stream>>>(
        Ud, MM, 0, MM,
        nullptr, 0, 0,
        Hbf, MM, (long)TT * MM,
        nullptr, 0,
        nullptr,
        UHbf, TT, (long)MM * TT);

    // ---- full decoder + final MLP (persistent) ----
    dec_persist<<<256, 256, 0, stream>>>(dec_data, UHbf, Hbf, WdT, vd, WdecT,
                                         dec_bih, dec_bhh, wt_w, wt_b,
                                         l1T, l1_b, l2_w, l2_b, (float*)d_out);
}